// Round 7
// baseline (391.648 us; speedup 1.0000x reference)
//
#include <hip/hip_runtime.h>

#define BATCH 2
#define SEQ 2048
#define EMBED 2048
#define NHEADS 32
#define NKV 8
#define HDIM 64
#define QKV_LD 3072  // fused [Q(2048) | K(512) | V(512)] row stride
#define LOG2E 1.44269504088896f

typedef __attribute__((ext_vector_type(8))) short short8;
typedef __attribute__((ext_vector_type(4))) float f32x4;

__device__ inline float hw_exp2(float x) { return __builtin_amdgcn_exp2f(x); }

__device__ inline ushort f2bf(float f) {
  union { float f; unsigned u; } v{f};
  unsigned r = v.u + 0x7FFF + ((v.u >> 16) & 1);
  return (ushort)(r >> 16);
}
__device__ inline float bf2f(ushort u) {
  union { unsigned u; float f; } v{((unsigned)u) << 16};
  return v.f;
}
__device__ inline unsigned fbits(float f) {
  union { float f; unsigned u; } v{f};
  return v.u;
}

__device__ inline void gload16(const ushort* g, ushort* l) {
  __builtin_amdgcn_global_load_lds(
      (const __attribute__((address_space(1))) unsigned*)g,
      (__attribute__((address_space(3))) unsigned*)l, 16, 0, 0);
}

// ---------------- fused fp32 -> bf16 convert (all 5 tensors, 1 launch) ----------------
__global__ __launch_bounds__(256) void cvt_all(const float* __restrict__ x,
                                               const float* __restrict__ wq,
                                               const float* __restrict__ wk,
                                               const float* __restrict__ wv,
                                               const float* __restrict__ wo,
                                               ushort* __restrict__ xb,
                                               ushort* __restrict__ wqkv,
                                               ushort* __restrict__ wob) {
  size_t e = (size_t)(blockIdx.x * blockDim.x + threadIdx.x) * 8;
  const float* src;
  ushort* dst;
  if (e < 8388608u) { src = x + e; dst = xb + e; }
  else if (e < 12582912u) { size_t o = e - 8388608u; src = wq + o; dst = wqkv + o; }
  else if (e < 13631488u) { size_t o = e - 12582912u; src = wk + o; dst = wqkv + 4194304u + o; }
  else if (e < 14680064u) { size_t o = e - 13631488u; src = wv + o; dst = wqkv + 5242880u + o; }
  else { size_t o = e - 14680064u; src = wo + o; dst = wob + o; }
  float4 v0 = ((const float4*)src)[0];
  float4 v1 = ((const float4*)src)[1];
  union { uint4 v; ushort u[8]; } pk;
  pk.u[0] = f2bf(v0.x); pk.u[1] = f2bf(v0.y); pk.u[2] = f2bf(v0.z); pk.u[3] = f2bf(v0.w);
  pk.u[4] = f2bf(v1.x); pk.u[5] = f2bf(v1.y); pk.u[6] = f2bf(v1.z); pk.u[7] = f2bf(v1.w);
  *(uint4*)dst = pk.v;
}

// ---------------- bf16 MFMA GEMM (m97 structure): C[M,N] = A * B^T ----------------
// DoRope: apply RoPE (+ exp2-domain Q prescale) in the epilogue for heads < 40.
// Each wave's 64-col span is exactly one 64-dim head (wave-uniform branch);
// dim pairs (d, d+32) are acc[i][j] / acc[i][j+2] in the same lane.
template <typename OutT, bool DoRope>
__global__ __launch_bounds__(256) void gemm_bf16(const ushort* __restrict__ A,
                                                 const ushort* __restrict__ B,
                                                 OutT* __restrict__ C,
                                                 int M, int N, int K,
                                                 const float* __restrict__ fc,
                                                 const float* __restrict__ fs) {
  __shared__ ushort As[128][32];
  __shared__ ushort Bs[128][32];
  const int tid = threadIdx.x;
  const int lane = tid & 63, wave = tid >> 6;
  const int quad = lane >> 4, l16 = lane & 15;
  const int m0 = blockIdx.y * 128, n0 = blockIdx.x * 128;
  const int wm = (wave >> 1) * 64, wn = (wave & 1) * 64;
  const int srow = lane >> 2, skq = (lane & 3) * 8;

  f32x4 acc[4][4] = {};
  for (int k0 = 0; k0 < K; k0 += 32) {
    const ushort* ga = A + (size_t)(m0 + wave * 32 + srow) * K + k0 + skq;
    const ushort* gb = B + (size_t)(n0 + wave * 32 + srow) * K + k0 + skq;
    __syncthreads();
    gload16(ga, &As[wave * 32][0]);
    gload16(ga + (size_t)16 * K, &As[wave * 32 + 16][0]);
    gload16(gb, &Bs[wave * 32][0]);
    gload16(gb + (size_t)16 * K, &Bs[wave * 32 + 16][0]);
    __syncthreads();
    short8 af[4], bf[4];
#pragma unroll
    for (int i = 0; i < 4; i++) af[i] = *(short8*)&As[wm + i * 16 + l16][quad * 8];
#pragma unroll
    for (int j = 0; j < 4; j++) bf[j] = *(short8*)&Bs[wn + j * 16 + l16][quad * 8];
#pragma unroll
    for (int i = 0; i < 4; i++)
#pragma unroll
      for (int j = 0; j < 4; j++)
        acc[i][j] = __builtin_amdgcn_mfma_f32_16x16x32_bf16(af[i], bf[j], acc[i][j], 0, 0, 0);
  }

  if constexpr (DoRope) {
    const int hd = (n0 + wn) >> 6;  // head index 0..47, wave-uniform
    if (hd < 40) {                  // Q heads (0..31) + K heads (32..39)
      const float scale = (hd < 32) ? 0.125f * LOG2E : 1.0f;
#pragma unroll
      for (int i = 0; i < 4; i++) {
#pragma unroll
        for (int r = 0; r < 4; r++) {
          int s = (m0 + wm + i * 16 + quad * 4 + r) & (SEQ - 1);
          const float* fcb = fc + s * HDIM + l16;
          const float* fsb = fs + s * HDIM + l16;
          float c0 = fcb[0], c1 = fcb[16], c2 = fcb[32], c3 = fcb[48];
          float s0 = fsb[0], s1 = fsb[16], s2 = fsb[32], s3 = fsb[48];
          float x0 = acc[i][0][r], x1 = acc[i][1][r];
          float x2 = acc[i][2][r], x3 = acc[i][3][r];
          acc[i][0][r] = (x0 * c0 - x2 * s0) * scale;
          acc[i][1][r] = (x1 * c1 - x3 * s1) * scale;
          acc[i][2][r] = (x2 * c2 + x0 * s2) * scale;
          acc[i][3][r] = (x3 * c3 + x1 * s3) * scale;
        }
      }
    }
  }

#pragma unroll
  for (int i = 0; i < 4; i++) {
#pragma unroll
    for (int r = 0; r < 4; r++) {
      size_t rg = (size_t)(m0 + wm + i * 16 + quad * 4 + r);
#pragma unroll
      for (int j = 0; j < 4; j++) {
        float v = acc[i][j][r];
        int cg = n0 + wn + j * 16 + l16;
        if constexpr (sizeof(OutT) == 2)
          C[rg * N + cg] = f2bf(v);
        else
          C[rg * N + cg] = v;
      }
    }
  }
}

// ---------------- MFMA flash attention, transposed-S, exp2 domain ----------------
__global__ __launch_bounds__(256) void attn_mfma(const ushort* __restrict__ QKV,
                                                 ushort* __restrict__ O) {
  __shared__ ushort Ks[64][72];     // [key][d]
  __shared__ ushort Vt[64][76];     // [d][key], stride 76 kills 8-way write conflicts
  __shared__ ushort Pw[4][16][72];  // per-wave P[q][key]
  const int tid = threadIdx.x;
  const int lane = tid & 63, wave = tid >> 6;
  const int quad = lane >> 4, l16 = lane & 15;
  const int bh = blockIdx.y;
  const int b = bh >> 5, h = bh & 31, kh = h >> 2;
  const int p = blockIdx.x;
  const int qt[2] = {p, 31 - p};
  const int ntiles = 32 - p;

  short8 qf[2][2];
#pragma unroll
  for (int u = 0; u < 2; u++)
#pragma unroll
    for (int c = 0; c < 2; c++)
      qf[u][c] = *(const short8*)(QKV +
          (size_t)(b * SEQ + qt[u] * 64 + wave * 16 + l16) * QKV_LD +
          h * HDIM + c * 32 + quad * 8);

  f32x4 o[2][4] = {};
  float m[2] = {-INFINITY, -INFINITY}, l[2] = {0.f, 0.f};

  const ushort* Kbase = QKV + (size_t)b * SEQ * QKV_LD + 2048 + kh * HDIM;
  const ushort* Vbase = Kbase + 512;
  const int kp = tid & 31, dg = tid >> 5;
  const int relrow = wave * 16 + l16;

  for (int t = 0; t < ntiles; t++) {
    const int k0 = t * 64;
    __syncthreads();
    {
      const float4* kpp = (const float4*)(Kbase + (size_t)(k0 + lane) * QKV_LD + wave * 16);
      float4 kv0 = kpp[0], kv1 = kpp[1];
      const uint4* va4 = (const uint4*)(Vbase + (size_t)(k0 + 2 * kp) * QKV_LD + dg * 8);
      const uint4* vb4 = (const uint4*)(Vbase + (size_t)(k0 + 2 * kp + 1) * QKV_LD + dg * 8);
      uint4 va = va4[0], vb = vb4[0];
      *(float4*)&Ks[lane][wave * 16] = kv0;
      *(float4*)&Ks[lane][wave * 16 + 8] = kv1;
      const unsigned* vaw = (const unsigned*)&va;
      const unsigned* vbw = (const unsigned*)&vb;
#pragma unroll
      for (int j = 0; j < 8; j++) {
        unsigned pk = (j & 1)
            ? __builtin_amdgcn_perm(vbw[j >> 1], vaw[j >> 1], 0x07060302)
            : __builtin_amdgcn_perm(vbw[j >> 1], vaw[j >> 1], 0x05040100);
        *(unsigned*)&Vt[dg * 8 + j][2 * kp] = pk;
      }
    }
    __syncthreads();

    // hoisted fragment loads: shared by both u subtiles (u=1 always active)
    short8 kf[4][2], vf[4][2];
#pragma unroll
    for (int nt = 0; nt < 4; nt++) {
      kf[nt][0] = *(short8*)&Ks[nt * 16 + l16][quad * 8];
      kf[nt][1] = *(short8*)&Ks[nt * 16 + l16][32 + quad * 8];
    }
#pragma unroll
    for (int dt = 0; dt < 4; dt++) {
      vf[dt][0] = *(short8*)&Vt[dt * 16 + l16][quad * 8];
      vf[dt][1] = *(short8*)&Vt[dt * 16 + l16][32 + quad * 8];
    }

#pragma unroll
    for (int u = 0; u < 2; u++) {
      const int diag = qt[u];
      if (t > diag) continue;

      f32x4 s[4];
#pragma unroll
      for (int nt = 0; nt < 4; nt++) {
        f32x4 z = {};
        z = __builtin_amdgcn_mfma_f32_16x16x32_bf16(kf[nt][0], qf[u][0], z, 0, 0, 0);
        s[nt] = __builtin_amdgcn_mfma_f32_16x16x32_bf16(kf[nt][1], qf[u][1], z, 0, 0, 0);
      }

      if (t == diag) {
#pragma unroll
        for (int nt = 0; nt < 4; nt++)
#pragma unroll
          for (int r = 0; r < 4; r++)
            if (nt * 16 + quad * 4 + r > relrow) s[nt][r] = -INFINITY;
      }

      float mx = -INFINITY;
#pragma unroll
      for (int nt = 0; nt < 4; nt++)
#pragma unroll
        for (int r = 0; r < 4; r++) mx = fmaxf(mx, s[nt][r]);
      mx = fmaxf(mx, __shfl_xor(mx, 16));
      mx = fmaxf(mx, __shfl_xor(mx, 32));
      float mnew = fmaxf(m[u], mx);

      if (!__all(mnew == m[u])) {  // wave-uniform fast path: max unchanged -> alpha==1
        float al = hw_exp2(m[u] - mnew);
        l[u] *= al;
#pragma unroll
        for (int dt = 0; dt < 4; dt++)
#pragma unroll
          for (int r = 0; r < 4; r++) o[u][dt][r] *= al;
        m[u] = mnew;
      }

      float pv[16];
      float psum = 0.f;
#pragma unroll
      for (int nt = 0; nt < 4; nt++)
#pragma unroll
        for (int r = 0; r < 4; r++) {
          float pe = hw_exp2(s[nt][r] - m[u]);
          pv[nt * 4 + r] = pe;
          psum += pe;
        }
      psum += __shfl_xor(psum, 16);
      psum += __shfl_xor(psum, 32);
      l[u] += psum;

#pragma unroll
      for (int nt = 0; nt < 4; nt++) {
        unsigned lo = __builtin_amdgcn_perm(fbits(pv[nt * 4 + 1]), fbits(pv[nt * 4 + 0]), 0x07060302);
        unsigned hi = __builtin_amdgcn_perm(fbits(pv[nt * 4 + 3]), fbits(pv[nt * 4 + 2]), 0x07060302);
        uint2 pk; pk.x = lo; pk.y = hi;
        *(uint2*)&Pw[wave][l16][nt * 16 + quad * 4] = pk;
      }
      short8 pf0 = *(short8*)&Pw[wave][l16][quad * 8];
      short8 pf1 = *(short8*)&Pw[wave][l16][32 + quad * 8];
#pragma unroll
      for (int dt = 0; dt < 4; dt++) {
        o[u][dt] = __builtin_amdgcn_mfma_f32_16x16x32_bf16(vf[dt][0], pf0, o[u][dt], 0, 0, 0);
        o[u][dt] = __builtin_amdgcn_mfma_f32_16x16x32_bf16(vf[dt][1], pf1, o[u][dt], 0, 0, 0);
      }
    }
  }

#pragma unroll
  for (int u = 0; u < 2; u++) {
    float inv = 1.0f / l[u];
    size_t rowg = (size_t)(b * SEQ + qt[u] * 64 + wave * 16 + l16) * EMBED + h * HDIM;
#pragma unroll
    for (int dt = 0; dt < 4; dt++) {
      ushort q0 = f2bf(o[u][dt][0] * inv), q1 = f2bf(o[u][dt][1] * inv);
      ushort q2 = f2bf(o[u][dt][2] * inv), q3 = f2bf(o[u][dt][3] * inv);
      uint2 pk;
      pk.x = (unsigned)q0 | ((unsigned)q1 << 16);
      pk.y = (unsigned)q2 | ((unsigned)q3 << 16);
      *(uint2*)&O[rowg + dt * 16 + quad * 4] = pk;
    }
  }
}

// ---------------- launch ----------------
extern "C" void kernel_launch(void* const* d_in, const int* in_sizes, int n_in,
                              void* d_out, int out_size, void* d_ws, size_t ws_size,
                              hipStream_t stream) {
  const float* x = (const float*)d_in[0];
  const float* fcos = (const float*)d_in[1];
  const float* fsin = (const float*)d_in[2];
  const float* wq = (const float*)d_in[3];
  const float* wk = (const float*)d_in[4];
  const float* wv = (const float*)d_in[5];
  const float* wo = (const float*)d_in[6];
  float* out = (float*)d_out;

  const int M = BATCH * SEQ;  // 4096
  ushort* ws = (ushort*)d_ws;
  ushort* xb = ws;
  ushort* wqkv = xb + (size_t)M * EMBED;
  ushort* wob = wqkv + (size_t)QKV_LD * EMBED;
  ushort* QKVb = wob + (size_t)EMBED * EMBED;
  ushort* Ab = QKVb + (size_t)M * QKV_LD;

  dim3 blk(256);
  cvt_all<<<9216, blk, 0, stream>>>(x, wq, wk, wv, wo, xb, wqkv, wob);

  // fused QKV projection with RoPE + Q prescale in epilogue
  gemm_bf16<ushort, true><<<dim3(QKV_LD / 128, M / 128), blk, 0, stream>>>(
      xb, wqkv, QKVb, M, QKV_LD, EMBED, fcos, fsin);

  attn_mfma<<<dim3(16, BATCH * NHEADS), blk, 0, stream>>>(QKVb, Ab);

  gemm_bf16<float, false><<<dim3(EMBED / 128, M / 128), blk, 0, stream>>>(
      Ab, wob, out, M, EMBED, EMBED, nullptr, nullptr);
}

// Round 8
// 355.397 us; speedup vs baseline: 1.1020x; 1.1020x over previous
//
#include <hip/hip_runtime.h>

#define BATCH 2
#define SEQ 2048
#define EMBED 2048
#define NHEADS 32
#define NKV 8
#define HDIM 64
#define QKV_LD 3072  // fused [Q(2048) | K(512) | V(512)] row stride
#define LOG2E 1.44269504088896f

typedef __attribute__((ext_vector_type(8))) short short8;
typedef __attribute__((ext_vector_type(4))) float f32x4;

__device__ inline float hw_exp2(float x) { return __builtin_amdgcn_exp2f(x); }

__device__ inline ushort f2bf(float f) {
  union { float f; unsigned u; } v{f};
  unsigned r = v.u + 0x7FFF + ((v.u >> 16) & 1);
  return (ushort)(r >> 16);
}
__device__ inline float bf2f(ushort u) {
  union { unsigned u; float f; } v{((unsigned)u) << 16};
  return v.f;
}
__device__ inline unsigned fbits(float f) {
  union { float f; unsigned u; } v{f};
  return v.u;
}

__device__ inline void gload16(const ushort* g, ushort* l) {
  __builtin_amdgcn_global_load_lds(
      (const __attribute__((address_space(1))) unsigned*)g,
      (__attribute__((address_space(3))) unsigned*)l, 16, 0, 0);
}

// ---------------- fused fp32 -> bf16 convert (all 5 tensors, 1 launch) ----------------
__global__ __launch_bounds__(256) void cvt_all(const float* __restrict__ x,
                                               const float* __restrict__ wq,
                                               const float* __restrict__ wk,
                                               const float* __restrict__ wv,
                                               const float* __restrict__ wo,
                                               ushort* __restrict__ xb,
                                               ushort* __restrict__ wqkv,
                                               ushort* __restrict__ wob) {
  size_t e = (size_t)(blockIdx.x * blockDim.x + threadIdx.x) * 8;
  const float* src;
  ushort* dst;
  if (e < 8388608u) { src = x + e; dst = xb + e; }
  else if (e < 12582912u) { size_t o = e - 8388608u; src = wq + o; dst = wqkv + o; }
  else if (e < 13631488u) { size_t o = e - 12582912u; src = wk + o; dst = wqkv + 4194304u + o; }
  else if (e < 14680064u) { size_t o = e - 13631488u; src = wv + o; dst = wqkv + 5242880u + o; }
  else { size_t o = e - 14680064u; src = wo + o; dst = wob + o; }
  float4 v0 = ((const float4*)src)[0];
  float4 v1 = ((const float4*)src)[1];
  union { uint4 v; ushort u[8]; } pk;
  pk.u[0] = f2bf(v0.x); pk.u[1] = f2bf(v0.y); pk.u[2] = f2bf(v0.z); pk.u[3] = f2bf(v0.w);
  pk.u[4] = f2bf(v1.x); pk.u[5] = f2bf(v1.y); pk.u[6] = f2bf(v1.z); pk.u[7] = f2bf(v1.w);
  *(uint4*)dst = pk.v;
}

// ---------------- bf16 MFMA GEMM (m97 structure): C[M,N] = A * B^T ----------------
template <typename OutT>
__global__ __launch_bounds__(256) void gemm_bf16(const ushort* __restrict__ A,
                                                 const ushort* __restrict__ B,
                                                 OutT* __restrict__ C,
                                                 int M, int N, int K) {
  __shared__ ushort As[128][32];
  __shared__ ushort Bs[128][32];
  const int tid = threadIdx.x;
  const int lane = tid & 63, wave = tid >> 6;
  const int quad = lane >> 4, l16 = lane & 15;
  const int m0 = blockIdx.y * 128, n0 = blockIdx.x * 128;
  const int wm = (wave >> 1) * 64, wn = (wave & 1) * 64;
  const int srow = lane >> 2, skq = (lane & 3) * 8;

  f32x4 acc[4][4] = {};
  for (int k0 = 0; k0 < K; k0 += 32) {
    const ushort* ga = A + (size_t)(m0 + wave * 32 + srow) * K + k0 + skq;
    const ushort* gb = B + (size_t)(n0 + wave * 32 + srow) * K + k0 + skq;
    __syncthreads();
    gload16(ga, &As[wave * 32][0]);
    gload16(ga + (size_t)16 * K, &As[wave * 32 + 16][0]);
    gload16(gb, &Bs[wave * 32][0]);
    gload16(gb + (size_t)16 * K, &Bs[wave * 32 + 16][0]);
    __syncthreads();
    short8 af[4], bf[4];
#pragma unroll
    for (int i = 0; i < 4; i++) af[i] = *(short8*)&As[wm + i * 16 + l16][quad * 8];
#pragma unroll
    for (int j = 0; j < 4; j++) bf[j] = *(short8*)&Bs[wn + j * 16 + l16][quad * 8];
#pragma unroll
    for (int i = 0; i < 4; i++)
#pragma unroll
      for (int j = 0; j < 4; j++)
        acc[i][j] = __builtin_amdgcn_mfma_f32_16x16x32_bf16(af[i], bf[j], acc[i][j], 0, 0, 0);
  }
#pragma unroll
  for (int i = 0; i < 4; i++) {
#pragma unroll
    for (int r = 0; r < 4; r++) {
      size_t rg = (size_t)(m0 + wm + i * 16 + quad * 4 + r);
#pragma unroll
      for (int j = 0; j < 4; j++) {
        float v = acc[i][j][r];
        int cg = n0 + wn + j * 16 + l16;
        if constexpr (sizeof(OutT) == 2)
          C[rg * N + cg] = f2bf(v);
        else
          C[rg * N + cg] = v;
      }
    }
  }
}

// ---------------- vectorized RoPE on fused QKV (Q prescaled by 0.125*log2e) ----------------
__global__ __launch_bounds__(256) void rope_qk(ushort* __restrict__ t,
                                               const float* __restrict__ fc,
                                               const float* __restrict__ fs,
                                               int total) {
  int idx = blockIdx.x * blockDim.x + threadIdx.x;
  if (idx >= total) return;
  int g = idx & 3;
  int hh = (idx >> 2) % 40;
  int tok = idx / 160;
  int s = tok & (SEQ - 1);
  float scale = (hh < 32) ? 0.125f * LOG2E : 1.0f;
  ushort* p = t + (size_t)tok * QKV_LD + hh * 64 + g * 8;
  union { uint4 v; ushort u[8]; } lo, hi, olo, ohi;
  lo.v = *(const uint4*)p;
  hi.v = *(const uint4*)(p + 32);
  const float* fcb = fc + s * HDIM + g * 8;
  const float* fsb = fs + s * HDIM + g * 8;
  float4 c0a = ((const float4*)fcb)[0], c0b = ((const float4*)fcb)[1];
  float4 s0a = ((const float4*)fsb)[0], s0b = ((const float4*)fsb)[1];
  float4 c1a = ((const float4*)(fcb + 32))[0], c1b = ((const float4*)(fcb + 32))[1];
  float4 s1a = ((const float4*)(fsb + 32))[0], s1b = ((const float4*)(fsb + 32))[1];
  float cc0[8] = {c0a.x, c0a.y, c0a.z, c0a.w, c0b.x, c0b.y, c0b.z, c0b.w};
  float ss0[8] = {s0a.x, s0a.y, s0a.z, s0a.w, s0b.x, s0b.y, s0b.z, s0b.w};
  float cc1[8] = {c1a.x, c1a.y, c1a.z, c1a.w, c1b.x, c1b.y, c1b.z, c1b.w};
  float ss1[8] = {s1a.x, s1a.y, s1a.z, s1a.w, s1b.x, s1b.y, s1b.z, s1b.w};
#pragma unroll
  for (int j = 0; j < 8; j++) {
    float x0 = bf2f(lo.u[j]), x1 = bf2f(hi.u[j]);
    olo.u[j] = f2bf((x0 * cc0[j] - x1 * ss0[j]) * scale);
    ohi.u[j] = f2bf((x1 * cc1[j] + x0 * ss1[j]) * scale);
  }
  *(uint4*)p = olo.v;
  *(uint4*)(p + 32) = ohi.v;
}

// ---------------- MFMA flash attention, transposed-S, exp2 domain ----------------
// Ks uses a 16B-granule XOR swizzle (granule ^= row&7) on an unpadded [64][64]:
// staging b128 writes and kf b128 reads both spread across all 8 granule
// columns -> conflict-free (row stride 128B would otherwise give 8-way).
__global__ __launch_bounds__(256) void attn_mfma(const ushort* __restrict__ QKV,
                                                 ushort* __restrict__ O) {
  __shared__ ushort Ks[64][64];     // [key][d], XOR-swizzled granules
  __shared__ ushort Vt[64][76];     // [d][key], stride 76 halves write conflicts
  __shared__ ushort Pw[4][16][72];  // per-wave P[q][key]
  const int tid = threadIdx.x;
  const int lane = tid & 63, wave = tid >> 6;
  const int quad = lane >> 4, l16 = lane & 15;
  const int bh = blockIdx.y;
  const int b = bh >> 5, h = bh & 31, kh = h >> 2;
  const int p = blockIdx.x;
  const int qt[2] = {p, 31 - p};
  const int ntiles = 32 - p;

  short8 qf[2][2];
#pragma unroll
  for (int u = 0; u < 2; u++)
#pragma unroll
    for (int c = 0; c < 2; c++)
      qf[u][c] = *(const short8*)(QKV +
          (size_t)(b * SEQ + qt[u] * 64 + wave * 16 + l16) * QKV_LD +
          h * HDIM + c * 32 + quad * 8);

  f32x4 o[2][4] = {};
  float m[2] = {-INFINITY, -INFINITY}, l[2] = {0.f, 0.f};

  const ushort* Kbase = QKV + (size_t)b * SEQ * QKV_LD + 2048 + kh * HDIM;
  const ushort* Vbase = Kbase + 512;
  const int kp = tid & 31, dg = tid >> 5;
  const int relrow = wave * 16 + l16;
  const int ksw = l16 & 7;  // kf-read swizzle key (row&7 == l16&7 since rows step by 16)

  for (int t = 0; t < ntiles; t++) {
    const int k0 = t * 64;
    __syncthreads();
    {
      const float4* kpp = (const float4*)(Kbase + (size_t)(k0 + lane) * QKV_LD + wave * 16);
      float4 kv0 = kpp[0], kv1 = kpp[1];
      const uint4* va4 = (const uint4*)(Vbase + (size_t)(k0 + 2 * kp) * QKV_LD + dg * 8);
      const uint4* vb4 = (const uint4*)(Vbase + (size_t)(k0 + 2 * kp + 1) * QKV_LD + dg * 8);
      uint4 va = va4[0], vb = vb4[0];
      const int g0 = ((wave * 2) ^ (lane & 7)) * 8;      // swizzled granule for d-slab 0
      const int g1 = ((wave * 2 + 1) ^ (lane & 7)) * 8;  // swizzled granule for d-slab 1
      *(float4*)&Ks[lane][g0] = kv0;
      *(float4*)&Ks[lane][g1] = kv1;
      const unsigned* vaw = (const unsigned*)&va;
      const unsigned* vbw = (const unsigned*)&vb;
#pragma unroll
      for (int j = 0; j < 8; j++) {
        unsigned pk = (j & 1)
            ? __builtin_amdgcn_perm(vbw[j >> 1], vaw[j >> 1], 0x07060302)
            : __builtin_amdgcn_perm(vbw[j >> 1], vaw[j >> 1], 0x05040100);
        *(unsigned*)&Vt[dg * 8 + j][2 * kp] = pk;
      }
    }
    __syncthreads();

#pragma unroll
    for (int u = 0; u < 2; u++) {
      const int diag = qt[u];
      if (t > diag) continue;

      f32x4 s[4];
#pragma unroll
      for (int nt = 0; nt < 4; nt++) {
        short8 kf0 = *(short8*)&Ks[nt * 16 + l16][(quad ^ ksw) * 8];
        short8 kf1 = *(short8*)&Ks[nt * 16 + l16][((quad + 4) ^ ksw) * 8];
        f32x4 z = {};
        z = __builtin_amdgcn_mfma_f32_16x16x32_bf16(kf0, qf[u][0], z, 0, 0, 0);
        s[nt] = __builtin_amdgcn_mfma_f32_16x16x32_bf16(kf1, qf[u][1], z, 0, 0, 0);
      }

      if (t == diag) {
#pragma unroll
        for (int nt = 0; nt < 4; nt++)
#pragma unroll
          for (int r = 0; r < 4; r++)
            if (nt * 16 + quad * 4 + r > relrow) s[nt][r] = -INFINITY;
      }

      float mx = -INFINITY;
#pragma unroll
      for (int nt = 0; nt < 4; nt++)
#pragma unroll
        for (int r = 0; r < 4; r++) mx = fmaxf(mx, s[nt][r]);
      mx = fmaxf(mx, __shfl_xor(mx, 16));
      mx = fmaxf(mx, __shfl_xor(mx, 32));
      float mnew = fmaxf(m[u], mx);

      if (!__all(mnew == m[u])) {  // wave-uniform fast path: alpha==1 when max stable
        float al = hw_exp2(m[u] - mnew);
        l[u] *= al;
#pragma unroll
        for (int dt = 0; dt < 4; dt++)
#pragma unroll
          for (int r = 0; r < 4; r++) o[u][dt][r] *= al;
        m[u] = mnew;
      }

      float pv[16];
      float psum = 0.f;
#pragma unroll
      for (int nt = 0; nt < 4; nt++)
#pragma unroll
        for (int r = 0; r < 4; r++) {
          float pe = hw_exp2(s[nt][r] - m[u]);
          pv[nt * 4 + r] = pe;
          psum += pe;
        }
      psum += __shfl_xor(psum, 16);
      psum += __shfl_xor(psum, 32);
      l[u] += psum;

#pragma unroll
      for (int nt = 0; nt < 4; nt++) {
        unsigned lo = __builtin_amdgcn_perm(fbits(pv[nt * 4 + 1]), fbits(pv[nt * 4 + 0]), 0x07060302);
        unsigned hi = __builtin_amdgcn_perm(fbits(pv[nt * 4 + 3]), fbits(pv[nt * 4 + 2]), 0x07060302);
        uint2 pk; pk.x = lo; pk.y = hi;
        *(uint2*)&Pw[wave][l16][nt * 16 + quad * 4] = pk;
      }
      short8 pf0 = *(short8*)&Pw[wave][l16][quad * 8];
      short8 pf1 = *(short8*)&Pw[wave][l16][32 + quad * 8];
#pragma unroll
      for (int dt = 0; dt < 4; dt++) {
        short8 vf0 = *(short8*)&Vt[dt * 16 + l16][quad * 8];
        short8 vf1 = *(short8*)&Vt[dt * 16 + l16][32 + quad * 8];
        o[u][dt] = __builtin_amdgcn_mfma_f32_16x16x32_bf16(vf0, pf0, o[u][dt], 0, 0, 0);
        o[u][dt] = __builtin_amdgcn_mfma_f32_16x16x32_bf16(vf1, pf1, o[u][dt], 0, 0, 0);
      }
    }
  }

#pragma unroll
  for (int u = 0; u < 2; u++) {
    float inv = 1.0f / l[u];
    size_t rowg = (size_t)(b * SEQ + qt[u] * 64 + wave * 16 + l16) * EMBED + h * HDIM;
#pragma unroll
    for (int dt = 0; dt < 4; dt++) {
      ushort q0 = f2bf(o[u][dt][0] * inv), q1 = f2bf(o[u][dt][1] * inv);
      ushort q2 = f2bf(o[u][dt][2] * inv), q3 = f2bf(o[u][dt][3] * inv);
      uint2 pk;
      pk.x = (unsigned)q0 | ((unsigned)q1 << 16);
      pk.y = (unsigned)q2 | ((unsigned)q3 << 16);
      *(uint2*)&O[rowg + dt * 16 + quad * 4] = pk;
    }
  }
}

// ---------------- launch ----------------
extern "C" void kernel_launch(void* const* d_in, const int* in_sizes, int n_in,
                              void* d_out, int out_size, void* d_ws, size_t ws_size,
                              hipStream_t stream) {
  const float* x = (const float*)d_in[0];
  const float* fcos = (const float*)d_in[1];
  const float* fsin = (const float*)d_in[2];
  const float* wq = (const float*)d_in[3];
  const float* wk = (const float*)d_in[4];
  const float* wv = (const float*)d_in[5];
  const float* wo = (const float*)d_in[6];
  float* out = (float*)d_out;

  const int M = BATCH * SEQ;  // 4096
  ushort* ws = (ushort*)d_ws;
  ushort* xb = ws;
  ushort* wqkv = xb + (size_t)M * EMBED;
  ushort* wob = wqkv + (size_t)QKV_LD * EMBED;
  ushort* QKVb = wob + (size_t)EMBED * EMBED;
  ushort* Ab = QKVb + (size_t)M * QKV_LD;

  dim3 blk(256);
  cvt_all<<<9216, blk, 0, stream>>>(x, wq, wk, wv, wo, xb, wqkv, wob);

  gemm_bf16<ushort><<<dim3(QKV_LD / 128, M / 128), blk, 0, stream>>>(xb, wqkv, QKVb, M, QKV_LD, EMBED);

  {
    int tot = M * 40 * 4;
    rope_qk<<<(tot + 255) / 256, blk, 0, stream>>>(QKVb, fcos, fsin, tot);
  }

  attn_mfma<<<dim3(16, BATCH * NHEADS), blk, 0, stream>>>(QKVb, Ab);

  gemm_bf16<float><<<dim3(EMBED / 128, M / 128), blk, 0, stream>>>(Ab, wob, out, M, EMBED, EMBED);
}